// Round 1
// baseline (5514.105 us; speedup 1.0000x reference)
//
#include <hip/hip_runtime.h>

#define N_NODES 50000
#define N_EDGES 800000
#define NUM_GRAPHS 16
#define NUM_CLASSES 247

static inline int nblk(long n) { return (int)((n + 255) / 256); }

// ---- degree / norm ----------------------------------------------------------
__global__ void k_deg(const int* __restrict__ col, float* __restrict__ deg, int E) {
    int e = blockIdx.x * blockDim.x + threadIdx.x;
    if (e < E) atomicAdd(&deg[col[e]], 1.0f);
}

__global__ void k_dinv(float* __restrict__ d, int N) {
    int v = blockIdx.x * blockDim.x + threadIdx.x;
    if (v < N) d[v] = rsqrtf(d[v] + 1.0f);  // +1 = self loop; deg>=1 always
}

// ---- dense: out[N,FOUT] = h[N,FIN] @ W[FIN,FOUT] ---------------------------
template <int FIN, int FOUT>
__global__ void k_linear(const float* __restrict__ h, const float* __restrict__ W,
                         float* __restrict__ out, int N) {
    long tid = (long)blockIdx.x * blockDim.x + threadIdx.x;
    if (tid >= (long)N * FOUT) return;
    int v = (int)(tid / FOUT);
    int f = (int)(tid % FOUT);
    const float* hr = h + (long)v * FIN;
    float s = 0.0f;
#pragma unroll 8
    for (int k = 0; k < FIN; ++k) s = fmaf(hr[k], W[k * FOUT + f], s);
    out[tid] = s;
}

// ---- agg init with self-loop term: agg[v] = dinv[v]^2 * hlin[v] ------------
template <int FOUT>
__global__ void k_init_agg(const float* __restrict__ hlin, const float* __restrict__ dinv,
                           float* __restrict__ agg, int N) {
    long tid = (long)blockIdx.x * blockDim.x + threadIdx.x;
    if (tid >= (long)N * FOUT) return;
    int v = (int)(tid / FOUT);
    float d = dinv[v];
    agg[tid] = d * d * hlin[tid];
}

// ---- edge scatter: agg[col] += dinv[row]*dinv[col] * hlin[row] -------------
template <int FOUT>
__global__ void k_scatter(const int* __restrict__ row, const int* __restrict__ col,
                          const float* __restrict__ dinv, const float* __restrict__ hlin,
                          float* __restrict__ agg, int E) {
    constexpr int GPE = FOUT / 4;  // float4 groups per edge
    long tid = (long)blockIdx.x * blockDim.x + threadIdx.x;
    if (tid >= (long)E * GPE) return;
    int e = (int)(tid / GPE);
    int g = (int)(tid % GPE);
    int r = row[e];
    int c = col[e];
    float nrm = dinv[r] * dinv[c];
    float4 v = *(const float4*)(hlin + (long)r * FOUT + g * 4);
    float* dst = agg + (long)c * FOUT + g * 4;
    atomicAdd(dst + 0, v.x * nrm);
    atomicAdd(dst + 1, v.y * nrm);
    atomicAdd(dst + 2, v.z * nrm);
    atomicAdd(dst + 3, v.w * nrm);
}

// ---- bias + relu (in place) -------------------------------------------------
template <int FOUT>
__global__ void k_bias_relu(float* __restrict__ h, const float* __restrict__ b, int N) {
    long tid = (long)blockIdx.x * blockDim.x + threadIdx.x;
    if (tid >= (long)N * FOUT) return;
    int f = (int)(tid % FOUT);
    float x = h[tid] + b[f];
    h[tid] = x > 0.0f ? x : 0.0f;
}

// ---- pooling: per-block LDS accumulate over 16 graphs ----------------------
#define POOL_CHUNK 512
__global__ void k_pool(const float* __restrict__ h, const int* __restrict__ batch,
                       float* __restrict__ psum, float* __restrict__ pcnt, int N) {
    __shared__ float acc[NUM_GRAPHS][256];
    __shared__ float scnt[NUM_GRAPHS];
    int tid = threadIdx.x;
    for (int g = 0; g < NUM_GRAPHS; ++g) acc[g][tid] = 0.0f;
    if (tid < NUM_GRAPHS) scnt[tid] = 0.0f;
    __syncthreads();
    int n0 = blockIdx.x * POOL_CHUNK;
    int n1 = n0 + POOL_CHUNK;
    if (n1 > N) n1 = N;
    for (int n = n0; n < n1; ++n) {
        int g = batch[n];                      // broadcast load, cached
        acc[g][tid] += h[(long)n * 256 + tid]; // thread tid owns column tid: no race
        if (tid == (n & 255)) atomicAdd(&scnt[g], 1.0f);
    }
    __syncthreads();
    for (int g = 0; g < NUM_GRAPHS; ++g) atomicAdd(&psum[g * 256 + tid], acc[g][tid]);
    if (tid < NUM_GRAPHS) atomicAdd(&pcnt[tid], scnt[tid]);
}

// ---- final FC: out[g,c] = (psum[g,:]/max(cnt,1)) @ Wfc + bfc ---------------
__global__ void k_fc(const float* __restrict__ psum, const float* __restrict__ pcnt,
                     const float* __restrict__ Wfc, const float* __restrict__ bfc,
                     float* __restrict__ out) {
    int tid = blockIdx.x * blockDim.x + threadIdx.x;
    if (tid >= NUM_GRAPHS * NUM_CLASSES) return;
    int g = tid / NUM_CLASSES;
    int c = tid % NUM_CLASSES;
    float s = 0.0f;
#pragma unroll 8
    for (int k = 0; k < 256; ++k) s = fmaf(psum[g * 256 + k], Wfc[k * NUM_CLASSES + c], s);
    float cnt = pcnt[g];
    cnt = cnt > 1.0f ? cnt : 1.0f;
    out[tid] = s / cnt + bfc[c];
}

extern "C" void kernel_launch(void* const* d_in, const int* in_sizes, int n_in,
                              void* d_out, int out_size, void* d_ws, size_t ws_size,
                              hipStream_t stream) {
    const float* x     = (const float*)d_in[0];
    const int*   ei    = (const int*)d_in[1];
    const int*   batch = (const int*)d_in[2];
    const float* W1    = (const float*)d_in[3];
    const float* b1    = (const float*)d_in[4];
    const float* W2    = (const float*)d_in[5];
    const float* b2    = (const float*)d_in[6];
    const float* W3    = (const float*)d_in[7];
    const float* b3    = (const float*)d_in[8];
    const float* Wfc   = (const float*)d_in[9];
    const float* bfc   = (const float*)d_in[10];
    float* out = (float*)d_out;

    const int* row = ei;            // edge_index[0] = src
    const int* col = ei + N_EDGES;  // edge_index[1] = dst

    // workspace layout (floats): 2*N*256 + N + 16*256 + 16  ~= 103 MB
    float* bufA = (float*)d_ws;                      // N*256  (agg / h)
    float* bufB = bufA + (size_t)N_NODES * 256;      // N*256  (hlin)
    float* dinv = bufB + (size_t)N_NODES * 256;      // N
    float* psum = dinv + N_NODES;                    // 16*256
    float* pcnt = psum + NUM_GRAPHS * 256;           // 16

    // ---- degree / dinv ----
    hipMemsetAsync(dinv, 0, N_NODES * sizeof(float), stream);
    hipMemsetAsync(psum, 0, (NUM_GRAPHS * 256 + NUM_GRAPHS) * sizeof(float), stream);
    k_deg<<<nblk(N_EDGES), 256, 0, stream>>>(col, dinv, N_EDGES);
    k_dinv<<<nblk(N_NODES), 256, 0, stream>>>(dinv, N_NODES);

    // ---- layer 1: 3 -> 64 ----
    k_linear<3, 64><<<nblk((long)N_NODES * 64), 256, 0, stream>>>(x, W1, bufB, N_NODES);
    k_init_agg<64><<<nblk((long)N_NODES * 64), 256, 0, stream>>>(bufB, dinv, bufA, N_NODES);
    k_scatter<64><<<nblk((long)N_EDGES * 16), 256, 0, stream>>>(row, col, dinv, bufB, bufA, N_EDGES);
    k_bias_relu<64><<<nblk((long)N_NODES * 64), 256, 0, stream>>>(bufA, b1, N_NODES);

    // ---- layer 2: 64 -> 128 ----
    k_linear<64, 128><<<nblk((long)N_NODES * 128), 256, 0, stream>>>(bufA, W2, bufB, N_NODES);
    k_init_agg<128><<<nblk((long)N_NODES * 128), 256, 0, stream>>>(bufB, dinv, bufA, N_NODES);
    k_scatter<128><<<nblk((long)N_EDGES * 32), 256, 0, stream>>>(row, col, dinv, bufB, bufA, N_EDGES);
    k_bias_relu<128><<<nblk((long)N_NODES * 128), 256, 0, stream>>>(bufA, b2, N_NODES);

    // ---- layer 3: 128 -> 256 ----
    k_linear<128, 256><<<nblk((long)N_NODES * 256), 256, 0, stream>>>(bufA, W3, bufB, N_NODES);
    k_init_agg<256><<<nblk((long)N_NODES * 256), 256, 0, stream>>>(bufB, dinv, bufA, N_NODES);
    k_scatter<256><<<nblk((long)N_EDGES * 64), 256, 0, stream>>>(row, col, dinv, bufB, bufA, N_EDGES);
    k_bias_relu<256><<<nblk((long)N_NODES * 256), 256, 0, stream>>>(bufA, b3, N_NODES);

    // ---- global mean pool + FC ----
    int pool_blocks = (N_NODES + POOL_CHUNK - 1) / POOL_CHUNK;
    k_pool<<<pool_blocks, 256, 0, stream>>>(bufA, batch, psum, pcnt, N_NODES);
    k_fc<<<nblk(NUM_GRAPHS * NUM_CLASSES), 256, 0, stream>>>(psum, pcnt, Wfc, bfc, out);
}

// Round 2
// 1000.445 us; speedup vs baseline: 5.5117x; 5.5117x over previous
//
#include <hip/hip_runtime.h>

#define N_NODES 50000
#define N_EDGES 800000
#define NUM_GRAPHS 16
#define NUM_CLASSES 247

static inline int nblk(long n) { return (int)((n + 255) / 256); }

// ---- degree histogram (int) ------------------------------------------------
__global__ void k_deg(const int* __restrict__ col, int* __restrict__ degi, int E) {
    int e = blockIdx.x * blockDim.x + threadIdx.x;
    if (e < E) atomicAdd(&degi[col[e]], 1);
}

__global__ void k_dinv(const int* __restrict__ degi, float* __restrict__ dinv, int N) {
    int v = blockIdx.x * blockDim.x + threadIdx.x;
    if (v < N) dinv[v] = rsqrtf((float)degi[v] + 1.0f);  // +1 = self loop
}

// ---- exclusive scan of degi -> rowptr[N+1], single block -------------------
__global__ void k_scan(const int* __restrict__ degi, int* __restrict__ rowptr, int N) {
    __shared__ int buf[1024];
    __shared__ int carry;
    if (threadIdx.x == 0) carry = 0;
    __syncthreads();
    for (int base = 0; base < N; base += 1024) {
        int i = base + (int)threadIdx.x;
        int v = (i < N) ? degi[i] : 0;
        buf[threadIdx.x] = v;
        __syncthreads();
        for (int off = 1; off < 1024; off <<= 1) {
            int t = 0;
            if ((int)threadIdx.x >= off) t = buf[threadIdx.x - off];
            __syncthreads();
            if ((int)threadIdx.x >= off) buf[threadIdx.x] += t;
            __syncthreads();
        }
        int incl = buf[threadIdx.x];
        if (i < N) rowptr[i] = carry + incl - v;  // exclusive
        __syncthreads();
        if (threadIdx.x == 0) carry += buf[1023];
        __syncthreads();
    }
    if (threadIdx.x == 0) rowptr[N] = carry;
}

// ---- CSR fill: csr_src[rowptr[c] + pos] = r --------------------------------
__global__ void k_fill(const int* __restrict__ row, const int* __restrict__ col,
                       const int* __restrict__ rowptr, int* __restrict__ cursor,
                       int* __restrict__ csr_src, int E) {
    int e = blockIdx.x * blockDim.x + threadIdx.x;
    if (e >= E) return;
    int c = col[e];
    int pos = atomicAdd(&cursor[c], 1);
    csr_src[rowptr[c] + pos] = row[e];
}

// ---- propagation, F=3 (raw x), thread per node -----------------------------
__global__ void k_prop3(const float* __restrict__ x, const float* __restrict__ dinv,
                        const int* __restrict__ rowptr, const int* __restrict__ csr_src,
                        float* __restrict__ out, int N) {
    int v = blockIdx.x * blockDim.x + threadIdx.x;
    if (v >= N) return;
    float dv = dinv[v];
    float a0 = dv * x[v * 3 + 0];
    float a1 = dv * x[v * 3 + 1];
    float a2 = dv * x[v * 3 + 2];
    int j1 = rowptr[v + 1];
    for (int j = rowptr[v]; j < j1; ++j) {
        int r = csr_src[j];
        float dr = dinv[r];
        a0 += dr * x[r * 3 + 0];
        a1 += dr * x[r * 3 + 1];
        a2 += dr * x[r * 3 + 2];
    }
    out[v * 3 + 0] = dv * a0;
    out[v * 3 + 1] = dv * a1;
    out[v * 3 + 2] = dv * a2;
}

// ---- propagation, F in {64,128}: wave per node, lane = feature -------------
// out[v] = dinv[v] * ( dinv[v]*h[v] + sum_{r in in(v)} dinv[r]*h[r] )
template <int F>
__global__ void k_prop(const float* __restrict__ h, const float* __restrict__ dinv,
                       const int* __restrict__ rowptr, const int* __restrict__ csr_src,
                       float* __restrict__ out, int N) {
    constexpr int K = F / 64;  // features per lane
    int wave = threadIdx.x >> 6;
    int lane = threadIdx.x & 63;
    int v = blockIdx.x * 4 + wave;  // 4 waves per 256-thread block
    if (v >= N) return;
    float dv = dinv[v];
    float acc[K];
#pragma unroll
    for (int k = 0; k < K; ++k) acc[k] = dv * h[(long)v * F + k * 64 + lane];
    int j0 = __builtin_amdgcn_readfirstlane(rowptr[v]);
    int j1 = __builtin_amdgcn_readfirstlane(rowptr[v + 1]);
    for (int j = j0; j < j1; ++j) {
        int r = __builtin_amdgcn_readfirstlane(csr_src[j]);
        float dr = dinv[r];
        const float* hr = h + (long)r * F;
#pragma unroll
        for (int k = 0; k < K; ++k) acc[k] += dr * hr[k * 64 + lane];
    }
#pragma unroll
    for (int k = 0; k < K; ++k) out[(long)v * F + k * 64 + lane] = dv * acc[k];
}

// ---- dense: out[N,FOUT] = relu?(h[N,FIN] @ W + b) --------------------------
template <int FIN, int FOUT, bool RELU>
__global__ void k_linear(const float* __restrict__ h, const float* __restrict__ W,
                         const float* __restrict__ b, float* __restrict__ out, int N) {
    long tid = (long)blockIdx.x * blockDim.x + threadIdx.x;
    if (tid >= (long)N * FOUT) return;
    int v = (int)(tid / FOUT);
    int f = (int)(tid % FOUT);
    const float* hr = h + (long)v * FIN;
    float s = b[f];
#pragma unroll 8
    for (int k = 0; k < FIN; ++k) s = fmaf(hr[k], W[k * FOUT + f], s);
    if (RELU) s = s > 0.0f ? s : 0.0f;
    out[tid] = s;
}

// ---- pooling: per-block LDS accumulate over 16 graphs ----------------------
#define POOL_CHUNK 512
__global__ void k_pool(const float* __restrict__ h, const int* __restrict__ batch,
                       float* __restrict__ psum, float* __restrict__ pcnt, int N) {
    __shared__ float acc[NUM_GRAPHS][256];
    __shared__ float scnt[NUM_GRAPHS];
    int tid = threadIdx.x;
    for (int g = 0; g < NUM_GRAPHS; ++g) acc[g][tid] = 0.0f;
    if (tid < NUM_GRAPHS) scnt[tid] = 0.0f;
    __syncthreads();
    int n0 = blockIdx.x * POOL_CHUNK;
    int n1 = n0 + POOL_CHUNK;
    if (n1 > N) n1 = N;
    for (int n = n0; n < n1; ++n) {
        int g = batch[n];
        acc[g][tid] += h[(long)n * 256 + tid];
        if (tid == (n & 255)) atomicAdd(&scnt[g], 1.0f);
    }
    __syncthreads();
    for (int g = 0; g < NUM_GRAPHS; ++g) atomicAdd(&psum[g * 256 + tid], acc[g][tid]);
    if (tid < NUM_GRAPHS) atomicAdd(&pcnt[tid], scnt[tid]);
}

// ---- final FC --------------------------------------------------------------
__global__ void k_fc(const float* __restrict__ psum, const float* __restrict__ pcnt,
                     const float* __restrict__ Wfc, const float* __restrict__ bfc,
                     float* __restrict__ out) {
    int tid = blockIdx.x * blockDim.x + threadIdx.x;
    if (tid >= NUM_GRAPHS * NUM_CLASSES) return;
    int g = tid / NUM_CLASSES;
    int c = tid % NUM_CLASSES;
    float s = 0.0f;
#pragma unroll 8
    for (int k = 0; k < 256; ++k) s = fmaf(psum[g * 256 + k], Wfc[k * NUM_CLASSES + c], s);
    float cnt = pcnt[g];
    cnt = cnt > 1.0f ? cnt : 1.0f;
    out[tid] = s / cnt + bfc[c];
}

extern "C" void kernel_launch(void* const* d_in, const int* in_sizes, int n_in,
                              void* d_out, int out_size, void* d_ws, size_t ws_size,
                              hipStream_t stream) {
    const float* x     = (const float*)d_in[0];
    const int*   ei    = (const int*)d_in[1];
    const int*   batch = (const int*)d_in[2];
    const float* W1    = (const float*)d_in[3];
    const float* b1    = (const float*)d_in[4];
    const float* W2    = (const float*)d_in[5];
    const float* b2    = (const float*)d_in[6];
    const float* W3    = (const float*)d_in[7];
    const float* b3    = (const float*)d_in[8];
    const float* Wfc   = (const float*)d_in[9];
    const float* bfc   = (const float*)d_in[10];
    float* out = (float*)d_out;

    const int* row = ei;            // src
    const int* col = ei + N_EDGES;  // dst

    // workspace layout (~81 MB)
    float* bufA   = (float*)d_ws;                        // N*256
    float* bufB   = bufA + (size_t)N_NODES * 256;        // N*128
    float* dinv   = bufB + (size_t)N_NODES * 128;        // N
    float* psum   = dinv + N_NODES;                      // 16*256
    float* pcnt   = psum + NUM_GRAPHS * 256;             // 16
    int*   degi   = (int*)(pcnt + NUM_GRAPHS);           // N
    int*   rowptr = degi + N_NODES;                      // N+1
    int*   cursor = rowptr + N_NODES + 1;                // N
    int*   csrsrc = cursor + N_NODES;                    // E

    hipMemsetAsync(degi, 0, N_NODES * sizeof(int), stream);
    hipMemsetAsync(cursor, 0, N_NODES * sizeof(int), stream);
    hipMemsetAsync(psum, 0, (NUM_GRAPHS * 256 + NUM_GRAPHS) * sizeof(float), stream);

    // ---- CSR build + norms ----
    k_deg<<<nblk(N_EDGES), 256, 0, stream>>>(col, degi, N_EDGES);
    k_dinv<<<nblk(N_NODES), 256, 0, stream>>>(degi, dinv, N_NODES);
    k_scan<<<1, 1024, 0, stream>>>(degi, rowptr, N_NODES);
    k_fill<<<nblk(N_EDGES), 256, 0, stream>>>(row, col, rowptr, cursor, csrsrc, N_EDGES);

    int prop_blocks = (N_NODES + 3) / 4;  // 4 nodes (waves) per block

    // ---- layer 1: p1 = A~ x  [N,3] -> h1 = relu(p1 W1 + b1) [N,64] ----
    k_prop3<<<nblk(N_NODES), 256, 0, stream>>>(x, dinv, rowptr, csrsrc, bufB, N_NODES);
    k_linear<3, 64, true><<<nblk((long)N_NODES * 64), 256, 0, stream>>>(bufB, W1, b1, bufA, N_NODES);

    // ---- layer 2: p2 = A~ h1 [N,64] -> h2 = relu(p2 W2 + b2) [N,128] ----
    k_prop<64><<<prop_blocks, 256, 0, stream>>>(bufA, dinv, rowptr, csrsrc, bufB, N_NODES);
    k_linear<64, 128, true><<<nblk((long)N_NODES * 128), 256, 0, stream>>>(bufB, W2, b2, bufA, N_NODES);

    // ---- layer 3: p3 = A~ h2 [N,128] -> h3 = relu(p3 W3 + b3) [N,256] ----
    k_prop<128><<<prop_blocks, 256, 0, stream>>>(bufA, dinv, rowptr, csrsrc, bufB, N_NODES);
    k_linear<128, 256, true><<<nblk((long)N_NODES * 256), 256, 0, stream>>>(bufB, W3, b3, bufA, N_NODES);

    // ---- global mean pool + FC ----
    int pool_blocks = (N_NODES + POOL_CHUNK - 1) / POOL_CHUNK;
    k_pool<<<pool_blocks, 256, 0, stream>>>(bufA, batch, psum, pcnt, N_NODES);
    k_fc<<<nblk(NUM_GRAPHS * NUM_CLASSES), 256, 0, stream>>>(psum, pcnt, Wfc, bfc, out);
}

// Round 3
// 478.447 us; speedup vs baseline: 11.5250x; 2.0910x over previous
//
#include <hip/hip_runtime.h>

#define N_NODES 50000
#define N_EDGES 800000
#define NUM_GRAPHS 16
#define NUM_CLASSES 247

static inline int nblk(long n) { return (int)((n + 255) / 256); }

// ---- degree histogram (int) ------------------------------------------------
__global__ void k_deg(const int* __restrict__ col, int* __restrict__ degi, int E) {
    int e = blockIdx.x * blockDim.x + threadIdx.x;
    if (e < E) atomicAdd(&degi[col[e]], 1);
}

__global__ void k_dinv(const int* __restrict__ degi, float* __restrict__ dinv, int N) {
    int v = blockIdx.x * blockDim.x + threadIdx.x;
    if (v < N) dinv[v] = rsqrtf((float)degi[v] + 1.0f);  // +1 = self loop
}

// ---- exclusive scan of degi -> rowptr[N+1], single block -------------------
__global__ void k_scan(const int* __restrict__ degi, int* __restrict__ rowptr, int N) {
    __shared__ int buf[1024];
    __shared__ int carry;
    if (threadIdx.x == 0) carry = 0;
    __syncthreads();
    for (int base = 0; base < N; base += 1024) {
        int i = base + (int)threadIdx.x;
        int v = (i < N) ? degi[i] : 0;
        buf[threadIdx.x] = v;
        __syncthreads();
        for (int off = 1; off < 1024; off <<= 1) {
            int t = 0;
            if ((int)threadIdx.x >= off) t = buf[threadIdx.x - off];
            __syncthreads();
            if ((int)threadIdx.x >= off) buf[threadIdx.x] += t;
            __syncthreads();
        }
        int incl = buf[threadIdx.x];
        if (i < N) rowptr[i] = carry + incl - v;  // exclusive
        __syncthreads();
        if (threadIdx.x == 0) carry += buf[1023];
        __syncthreads();
    }
    if (threadIdx.x == 0) rowptr[N] = carry;
}

// ---- CSR fill: csr_src[rowptr[c] + pos] = r --------------------------------
__global__ void k_fill(const int* __restrict__ row, const int* __restrict__ col,
                       const int* __restrict__ rowptr, int* __restrict__ cursor,
                       int* __restrict__ csr_src, int E) {
    int e = blockIdx.x * blockDim.x + threadIdx.x;
    if (e >= E) return;
    int c = col[e];
    int pos = atomicAdd(&cursor[c], 1);
    csr_src[rowptr[c] + pos] = row[e];
}

// ---- propagation, F=3 (raw x), thread per node -----------------------------
__global__ void k_prop3(const float* __restrict__ x, const float* __restrict__ dinv,
                        const int* __restrict__ rowptr, const int* __restrict__ csr_src,
                        float* __restrict__ out, int N) {
    int v = blockIdx.x * blockDim.x + threadIdx.x;
    if (v >= N) return;
    float dv = dinv[v];
    float a0 = dv * x[v * 3 + 0];
    float a1 = dv * x[v * 3 + 1];
    float a2 = dv * x[v * 3 + 2];
    int j1 = rowptr[v + 1];
    for (int j = rowptr[v]; j < j1; ++j) {
        int r = csr_src[j];
        float dr = dinv[r];
        a0 += dr * x[r * 3 + 0];
        a1 += dr * x[r * 3 + 1];
        a2 += dr * x[r * 3 + 2];
    }
    out[v * 3 + 0] = dv * a0;
    out[v * 3 + 1] = dv * a1;
    out[v * 3 + 2] = dv * a2;
}

// ---- propagation, F in {64,128}: wave per node, lane = K contiguous floats -
// out[v] = dinv[v] * ( dinv[v]*h[v] + sum_{r in in(v)} dinv[r]*h[r] )
// CSR bounds / indices / dinv[r] are wave-uniform -> scalar pipe; 4-edge unroll
// keeps 4 independent row loads in flight.
template <int F>
__global__ __launch_bounds__(256) void k_prop(
        const float* __restrict__ h, const float* __restrict__ dinv,
        const int* __restrict__ rowptr, const int* __restrict__ csr_src,
        float* __restrict__ out, int N) {
    constexpr int K = F / 64;  // contiguous floats per lane (1 or 2)
    int wave = threadIdx.x >> 6;
    int lane = threadIdx.x & 63;
    int v = blockIdx.x * 4 + wave;
    if (v >= N) return;
    float dv = dinv[v];
    float acc[K];
    const float* hv = h + (long)v * F + lane * K;
#pragma unroll
    for (int k = 0; k < K; ++k) acc[k] = dv * hv[k];
    int j0 = __builtin_amdgcn_readfirstlane(rowptr[v]);
    int j1 = __builtin_amdgcn_readfirstlane(rowptr[v + 1]);
    int j = j0;
    for (; j + 4 <= j1; j += 4) {
        int r0 = csr_src[j + 0], r1 = csr_src[j + 1];
        int r2 = csr_src[j + 2], r3 = csr_src[j + 3];
        float d0 = dinv[r0], d1 = dinv[r1], d2 = dinv[r2], d3 = dinv[r3];
        const float* h0 = h + (long)r0 * F + lane * K;
        const float* h1 = h + (long)r1 * F + lane * K;
        const float* h2 = h + (long)r2 * F + lane * K;
        const float* h3 = h + (long)r3 * F + lane * K;
#pragma unroll
        for (int k = 0; k < K; ++k) {
            float t0 = h0[k], t1 = h1[k], t2 = h2[k], t3 = h3[k];
            acc[k] = fmaf(d0, t0, acc[k]);
            acc[k] = fmaf(d1, t1, acc[k]);
            acc[k] = fmaf(d2, t2, acc[k]);
            acc[k] = fmaf(d3, t3, acc[k]);
        }
    }
    for (; j < j1; ++j) {
        int r = csr_src[j];
        float dr = dinv[r];
        const float* hr = h + (long)r * F + lane * K;
#pragma unroll
        for (int k = 0; k < K; ++k) acc[k] = fmaf(dr, hr[k], acc[k]);
    }
    float* ov = out + (long)v * F + lane * K;
#pragma unroll
    for (int k = 0; k < K; ++k) ov[k] = dv * acc[k];
}

// ---- naive linear for tiny FIN=3 layer -------------------------------------
__global__ void k_lin3(const float* __restrict__ h, const float* __restrict__ W,
                       const float* __restrict__ b, float* __restrict__ out, int N) {
    long tid = (long)blockIdx.x * blockDim.x + threadIdx.x;
    if (tid >= (long)N * 64) return;
    int v = (int)(tid / 64);
    int f = (int)(tid % 64);
    const float* hr = h + (long)v * 3;
    float s = b[f];
    s = fmaf(hr[0], W[0 * 64 + f], s);
    s = fmaf(hr[1], W[1 * 64 + f], s);
    s = fmaf(hr[2], W[2 * 64 + f], s);
    out[tid] = s > 0.0f ? s : 0.0f;
}

// ---- register-tiled GEMM: out[N,FOUT] = relu(h[N,FIN] @ W + b) -------------
// Tile: 32 nodes x FOUT, K=FIN. 256 threads = (FOUT/4) f-groups x VG v-groups.
// Per k: 1 global float4 (W, L1/L2-hit coalesced) + VPT LDS broadcasts
// (merge to ds_read_b128 under unroll-4) feeding 4*VPT fma.
template <int FIN, int FOUT, bool RELU>
__global__ __launch_bounds__(256) void k_gemm(
        const float* __restrict__ h, const float* __restrict__ W,
        const float* __restrict__ b, float* __restrict__ out, int N) {
    constexpr int FG = FOUT / 4;    // f-groups (float4)
    constexpr int VG = 256 / FG;    // v-groups
    constexpr int VPT = 32 / VG;    // nodes per thread
    constexpr int ROWF4 = FIN / 4;  // float4s per h row
    __shared__ float hs[32][FIN];   // FIN=128 -> 16 KB
    int t = threadIdx.x;
    int fg = t % FG;
    int vg = t / FG;
    int v0 = blockIdx.x * 32;
    for (int i = t; i < 32 * ROWF4; i += 256) {
        int vv = i / ROWF4, kk = i % ROWF4;
        int vsrc = v0 + vv;
        if (vsrc >= N) vsrc = N - 1;  // tail: clamp, stores are guarded
        float4 val = ((const float4*)(h + (long)vsrc * FIN))[kk];
        *(float4*)&hs[vv][kk * 4] = val;
    }
    __syncthreads();
    float4 bias = ((const float4*)b)[fg];
    float acc[VPT][4];
#pragma unroll
    for (int i = 0; i < VPT; ++i) {
        acc[i][0] = bias.x; acc[i][1] = bias.y;
        acc[i][2] = bias.z; acc[i][3] = bias.w;
    }
    const float4* Wf4 = (const float4*)W;
#pragma unroll 4
    for (int k = 0; k < FIN; ++k) {
        float4 w = Wf4[k * FG + fg];
#pragma unroll
        for (int i = 0; i < VPT; ++i) {
            float hv = hs[vg * VPT + i][k];
            acc[i][0] = fmaf(hv, w.x, acc[i][0]);
            acc[i][1] = fmaf(hv, w.y, acc[i][1]);
            acc[i][2] = fmaf(hv, w.z, acc[i][2]);
            acc[i][3] = fmaf(hv, w.w, acc[i][3]);
        }
    }
#pragma unroll
    for (int i = 0; i < VPT; ++i) {
        int v = v0 + vg * VPT + i;
        if (v < N) {
            float4 r;
            r.x = RELU ? fmaxf(acc[i][0], 0.0f) : acc[i][0];
            r.y = RELU ? fmaxf(acc[i][1], 0.0f) : acc[i][1];
            r.z = RELU ? fmaxf(acc[i][2], 0.0f) : acc[i][2];
            r.w = RELU ? fmaxf(acc[i][3], 0.0f) : acc[i][3];
            ((float4*)(out + (long)v * FOUT))[fg] = r;
        }
    }
}

// ---- graph-size histogram (counts), LDS-staged -----------------------------
__global__ void k_cnt(const int* __restrict__ batch, float* __restrict__ pcnt, int N) {
    __shared__ int hist[NUM_GRAPHS];
    if (threadIdx.x < NUM_GRAPHS) hist[threadIdx.x] = 0;
    __syncthreads();
    int v = blockIdx.x * blockDim.x + threadIdx.x;
    if (v < N) atomicAdd(&hist[batch[v]], 1);
    __syncthreads();
    if (threadIdx.x < NUM_GRAPHS && hist[threadIdx.x] > 0)
        atomicAdd(&pcnt[threadIdx.x], (float)hist[threadIdx.x]);
}

// ---- pooling: 64 nodes/block, register accumulator, flush on graph change --
#define POOL_CHUNK 64
__global__ __launch_bounds__(256) void k_pool(
        const float* __restrict__ h, const int* __restrict__ batch,
        float* __restrict__ psum, int N) {
    int tid = threadIdx.x;  // feature
    int n0 = blockIdx.x * POOL_CHUNK;
    int n1 = n0 + POOL_CHUNK;
    if (n1 > N) n1 = N;
    int gcur = batch[n0];  // sorted -> uniform scalar
    float racc = 0.0f;
    for (int n = n0; n < n1; ++n) {
        int g = batch[n];
        if (g != gcur) {
            atomicAdd(&psum[gcur * 256 + tid], racc);
            racc = 0.0f;
            gcur = g;
        }
        racc += h[(long)n * 256 + tid];
    }
    atomicAdd(&psum[gcur * 256 + tid], racc);
}

// ---- final FC --------------------------------------------------------------
__global__ void k_fc(const float* __restrict__ psum, const float* __restrict__ pcnt,
                     const float* __restrict__ Wfc, const float* __restrict__ bfc,
                     float* __restrict__ out) {
    int tid = blockIdx.x * blockDim.x + threadIdx.x;
    if (tid >= NUM_GRAPHS * NUM_CLASSES) return;
    int g = tid / NUM_CLASSES;
    int c = tid % NUM_CLASSES;
    float s = 0.0f;
#pragma unroll 8
    for (int k = 0; k < 256; ++k) s = fmaf(psum[g * 256 + k], Wfc[k * NUM_CLASSES + c], s);
    float cnt = pcnt[g];
    cnt = cnt > 1.0f ? cnt : 1.0f;
    out[tid] = s / cnt + bfc[c];
}

extern "C" void kernel_launch(void* const* d_in, const int* in_sizes, int n_in,
                              void* d_out, int out_size, void* d_ws, size_t ws_size,
                              hipStream_t stream) {
    const float* x     = (const float*)d_in[0];
    const int*   ei    = (const int*)d_in[1];
    const int*   batch = (const int*)d_in[2];
    const float* W1    = (const float*)d_in[3];
    const float* b1    = (const float*)d_in[4];
    const float* W2    = (const float*)d_in[5];
    const float* b2    = (const float*)d_in[6];
    const float* W3    = (const float*)d_in[7];
    const float* b3    = (const float*)d_in[8];
    const float* Wfc   = (const float*)d_in[9];
    const float* bfc   = (const float*)d_in[10];
    float* out = (float*)d_out;

    const int* row = ei;            // src
    const int* col = ei + N_EDGES;  // dst

    // workspace layout (~81 MB)
    float* bufA   = (float*)d_ws;                        // N*256
    float* bufB   = bufA + (size_t)N_NODES * 256;        // N*128
    float* dinv   = bufB + (size_t)N_NODES * 128;        // N
    float* psum   = dinv + N_NODES;                      // 16*256
    float* pcnt   = psum + NUM_GRAPHS * 256;             // 16
    int*   degi   = (int*)(pcnt + NUM_GRAPHS);           // N
    int*   rowptr = degi + N_NODES;                      // N+1
    int*   cursor = rowptr + N_NODES + 1;                // N
    int*   csrsrc = cursor + N_NODES;                    // E

    hipMemsetAsync(degi, 0, N_NODES * sizeof(int), stream);
    hipMemsetAsync(cursor, 0, N_NODES * sizeof(int), stream);
    hipMemsetAsync(psum, 0, (NUM_GRAPHS * 256 + NUM_GRAPHS) * sizeof(float), stream);

    // ---- CSR build + norms ----
    k_deg<<<nblk(N_EDGES), 256, 0, stream>>>(col, degi, N_EDGES);
    k_dinv<<<nblk(N_NODES), 256, 0, stream>>>(degi, dinv, N_NODES);
    k_scan<<<1, 1024, 0, stream>>>(degi, rowptr, N_NODES);
    k_fill<<<nblk(N_EDGES), 256, 0, stream>>>(row, col, rowptr, cursor, csrsrc, N_EDGES);

    int prop_blocks = (N_NODES + 3) / 4;   // 4 nodes (waves) per block
    int gemm_blocks = (N_NODES + 31) / 32; // 32-node tiles

    // ---- layer 1: p1 = A~ x [N,3]; h1 = relu(p1 W1 + b1) [N,64] ----
    k_prop3<<<nblk(N_NODES), 256, 0, stream>>>(x, dinv, rowptr, csrsrc, bufB, N_NODES);
    k_lin3<<<nblk((long)N_NODES * 64), 256, 0, stream>>>(bufB, W1, b1, bufA, N_NODES);

    // ---- layer 2: p2 = A~ h1 [N,64]; h2 = relu(p2 W2 + b2) [N,128] ----
    k_prop<64><<<prop_blocks, 256, 0, stream>>>(bufA, dinv, rowptr, csrsrc, bufB, N_NODES);
    k_gemm<64, 128, true><<<gemm_blocks, 256, 0, stream>>>(bufB, W2, b2, bufA, N_NODES);

    // ---- layer 3: p3 = A~ h2 [N,128]; h3 = relu(p3 W3 + b3) [N,256] ----
    k_prop<128><<<prop_blocks, 256, 0, stream>>>(bufA, dinv, rowptr, csrsrc, bufB, N_NODES);
    k_gemm<128, 256, true><<<gemm_blocks, 256, 0, stream>>>(bufB, W3, b3, bufA, N_NODES);

    // ---- global mean pool + FC ----
    k_cnt<<<nblk(N_NODES), 256, 0, stream>>>(batch, pcnt, N_NODES);
    int pool_blocks = (N_NODES + POOL_CHUNK - 1) / POOL_CHUNK;
    k_pool<<<pool_blocks, 256, 0, stream>>>(bufA, batch, psum, N_NODES);
    k_fc<<<nblk(NUM_GRAPHS * NUM_CLASSES), 256, 0, stream>>>(psum, pcnt, Wfc, bfc, out);
}

// Round 4
// 388.945 us; speedup vs baseline: 14.1771x; 1.2301x over previous
//
#include <hip/hip_runtime.h>

#define N_NODES 50000
#define N_EDGES 800000
#define NUM_GRAPHS 16
#define NUM_CLASSES 247
#define SCAN_BLOCKS ((N_NODES + 255) / 256)  // 196

static inline int nblk(long n) { return (int)((n + 255) / 256); }

// ---- degree histogram (int) ------------------------------------------------
__global__ void k_deg(const int* __restrict__ col, int* __restrict__ degi, int E) {
    int e = blockIdx.x * blockDim.x + threadIdx.x;
    if (e < E) atomicAdd(&degi[col[e]], 1);
}

__global__ void k_dinv(const int* __restrict__ degi, float* __restrict__ dinv, int N) {
    int v = blockIdx.x * blockDim.x + threadIdx.x;
    if (v < N) dinv[v] = rsqrtf((float)degi[v] + 1.0f);  // +1 = self loop
}

// ---- hierarchical exclusive scan: degi -> rowptr[N+1] ----------------------
// phase 1: per-block LDS scan, write exclusive + block sum
__global__ __launch_bounds__(256) void k_scan1(const int* __restrict__ degi,
                                               int* __restrict__ rowptr,
                                               int* __restrict__ bsum, int N) {
    __shared__ int buf[256];
    int t = threadIdx.x;
    int i = blockIdx.x * 256 + t;
    int v = (i < N) ? degi[i] : 0;
    buf[t] = v;
    __syncthreads();
#pragma unroll
    for (int off = 1; off < 256; off <<= 1) {
        int tmp = (t >= off) ? buf[t - off] : 0;
        __syncthreads();
        if (t >= off) buf[t] += tmp;
        __syncthreads();
    }
    if (i < N) rowptr[i] = buf[t] - v;  // exclusive within block
    if (t == 255) bsum[blockIdx.x] = buf[255];
}

// phase 2: scan the block sums (SCAN_BLOCKS <= 256), single block
__global__ __launch_bounds__(256) void k_scan2(int* __restrict__ bsum, int nb) {
    __shared__ int buf[256];
    int t = threadIdx.x;
    int v = (t < nb) ? bsum[t] : 0;
    buf[t] = v;
    __syncthreads();
#pragma unroll
    for (int off = 1; off < 256; off <<= 1) {
        int tmp = (t >= off) ? buf[t - off] : 0;
        __syncthreads();
        if (t >= off) buf[t] += tmp;
        __syncthreads();
    }
    if (t < nb) bsum[t] = buf[t] - v;  // exclusive
}

// phase 3: add block offsets; rowptr[N] = total in-degree = N_EDGES
__global__ __launch_bounds__(256) void k_scan3(int* __restrict__ rowptr,
                                               const int* __restrict__ bsum, int N) {
    int i = blockIdx.x * 256 + (int)threadIdx.x;
    if (i < N) rowptr[i] += bsum[blockIdx.x];
    if (i == 0) rowptr[N] = N_EDGES;
}

// ---- CSR fill: csr_src[rowptr[c] + pos] = r --------------------------------
__global__ void k_fill(const int* __restrict__ row, const int* __restrict__ col,
                       const int* __restrict__ rowptr, int* __restrict__ cursor,
                       int* __restrict__ csr_src, int E) {
    int e = blockIdx.x * blockDim.x + threadIdx.x;
    if (e >= E) return;
    int c = col[e];
    int pos = atomicAdd(&cursor[c], 1);
    csr_src[rowptr[c] + pos] = row[e];
}

// ---- propagation, F=3 (raw x), thread per node -----------------------------
__global__ void k_prop3(const float* __restrict__ x, const float* __restrict__ dinv,
                        const int* __restrict__ rowptr, const int* __restrict__ csr_src,
                        float* __restrict__ out, int N) {
    int v = blockIdx.x * blockDim.x + threadIdx.x;
    if (v >= N) return;
    float dv = dinv[v];
    float a0 = dv * x[v * 3 + 0];
    float a1 = dv * x[v * 3 + 1];
    float a2 = dv * x[v * 3 + 2];
    int j1 = rowptr[v + 1];
    for (int j = rowptr[v]; j < j1; ++j) {
        int r = csr_src[j];
        float dr = dinv[r];
        a0 += dr * x[r * 3 + 0];
        a1 += dr * x[r * 3 + 1];
        a2 += dr * x[r * 3 + 2];
    }
    out[v * 3 + 0] = dv * a0;
    out[v * 3 + 1] = dv * a1;
    out[v * 3 + 2] = dv * a2;
}

// ---- propagation, F in {64,128}: wave per node, lane = K contiguous floats -
template <int F>
__global__ __launch_bounds__(256) void k_prop(
        const float* __restrict__ h, const float* __restrict__ dinv,
        const int* __restrict__ rowptr, const int* __restrict__ csr_src,
        float* __restrict__ out, int N) {
    constexpr int K = F / 64;  // contiguous floats per lane (1 or 2)
    int wave = threadIdx.x >> 6;
    int lane = threadIdx.x & 63;
    int v = blockIdx.x * 4 + wave;
    if (v >= N) return;
    float dv = dinv[v];
    float acc[K];
    const float* hv = h + (long)v * F + lane * K;
#pragma unroll
    for (int k = 0; k < K; ++k) acc[k] = dv * hv[k];
    int j0 = __builtin_amdgcn_readfirstlane(rowptr[v]);
    int j1 = __builtin_amdgcn_readfirstlane(rowptr[v + 1]);
    int j = j0;
    for (; j + 4 <= j1; j += 4) {
        int r0 = csr_src[j + 0], r1 = csr_src[j + 1];
        int r2 = csr_src[j + 2], r3 = csr_src[j + 3];
        float d0 = dinv[r0], d1 = dinv[r1], d2 = dinv[r2], d3 = dinv[r3];
        const float* h0 = h + (long)r0 * F + lane * K;
        const float* h1 = h + (long)r1 * F + lane * K;
        const float* h2 = h + (long)r2 * F + lane * K;
        const float* h3 = h + (long)r3 * F + lane * K;
#pragma unroll
        for (int k = 0; k < K; ++k) {
            float t0 = h0[k], t1 = h1[k], t2 = h2[k], t3 = h3[k];
            acc[k] = fmaf(d0, t0, acc[k]);
            acc[k] = fmaf(d1, t1, acc[k]);
            acc[k] = fmaf(d2, t2, acc[k]);
            acc[k] = fmaf(d3, t3, acc[k]);
        }
    }
    for (; j < j1; ++j) {
        int r = csr_src[j];
        float dr = dinv[r];
        const float* hr = h + (long)r * F + lane * K;
#pragma unroll
        for (int k = 0; k < K; ++k) acc[k] = fmaf(dr, hr[k], acc[k]);
    }
    float* ov = out + (long)v * F + lane * K;
#pragma unroll
    for (int k = 0; k < K; ++k) ov[k] = dv * acc[k];
}

// ---- naive linear for tiny FIN=3 layer -------------------------------------
__global__ void k_lin3(const float* __restrict__ h, const float* __restrict__ W,
                       const float* __restrict__ b, float* __restrict__ out, int N) {
    long tid = (long)blockIdx.x * blockDim.x + threadIdx.x;
    if (tid >= (long)N * 64) return;
    int v = (int)(tid / 64);
    int f = (int)(tid % 64);
    const float* hr = h + (long)v * 3;
    float s = b[f];
    s = fmaf(hr[0], W[0 * 64 + f], s);
    s = fmaf(hr[1], W[1 * 64 + f], s);
    s = fmaf(hr[2], W[2 * 64 + f], s);
    out[tid] = s > 0.0f ? s : 0.0f;
}

// ---- register-tiled GEMM: out[N,FOUT] = relu(h[N,FIN] @ W + b) -------------
template <int FIN, int FOUT, bool RELU>
__global__ __launch_bounds__(256) void k_gemm(
        const float* __restrict__ h, const float* __restrict__ W,
        const float* __restrict__ b, float* __restrict__ out, int N) {
    constexpr int FG = FOUT / 4;    // f-groups (float4)
    constexpr int VG = 256 / FG;    // v-groups
    constexpr int VPT = 32 / VG;    // nodes per thread
    constexpr int ROWF4 = FIN / 4;  // float4s per h row
    __shared__ float hs[32][FIN];   // FIN=128 -> 16 KB
    int t = threadIdx.x;
    int fg = t % FG;
    int vg = t / FG;
    int v0 = blockIdx.x * 32;
    for (int i = t; i < 32 * ROWF4; i += 256) {
        int vv = i / ROWF4, kk = i % ROWF4;
        int vsrc = v0 + vv;
        if (vsrc >= N) vsrc = N - 1;  // tail: clamp, stores are guarded
        float4 val = ((const float4*)(h + (long)vsrc * FIN))[kk];
        *(float4*)&hs[vv][kk * 4] = val;
    }
    __syncthreads();
    float4 bias = ((const float4*)b)[fg];
    float acc[VPT][4];
#pragma unroll
    for (int i = 0; i < VPT; ++i) {
        acc[i][0] = bias.x; acc[i][1] = bias.y;
        acc[i][2] = bias.z; acc[i][3] = bias.w;
    }
    const float4* Wf4 = (const float4*)W;
#pragma unroll 4
    for (int k = 0; k < FIN; ++k) {
        float4 w = Wf4[k * FG + fg];
#pragma unroll
        for (int i = 0; i < VPT; ++i) {
            float hv = hs[vg * VPT + i][k];
            acc[i][0] = fmaf(hv, w.x, acc[i][0]);
            acc[i][1] = fmaf(hv, w.y, acc[i][1]);
            acc[i][2] = fmaf(hv, w.z, acc[i][2]);
            acc[i][3] = fmaf(hv, w.w, acc[i][3]);
        }
    }
#pragma unroll
    for (int i = 0; i < VPT; ++i) {
        int v = v0 + vg * VPT + i;
        if (v < N) {
            float4 r;
            r.x = RELU ? fmaxf(acc[i][0], 0.0f) : acc[i][0];
            r.y = RELU ? fmaxf(acc[i][1], 0.0f) : acc[i][1];
            r.z = RELU ? fmaxf(acc[i][2], 0.0f) : acc[i][2];
            r.w = RELU ? fmaxf(acc[i][3], 0.0f) : acc[i][3];
            ((float4*)(out + (long)v * FOUT))[fg] = r;
        }
    }
}

// ---- graph-size histogram (counts), LDS-staged -----------------------------
__global__ void k_cnt(const int* __restrict__ batch, float* __restrict__ pcnt, int N) {
    __shared__ int hist[NUM_GRAPHS];
    if (threadIdx.x < NUM_GRAPHS) hist[threadIdx.x] = 0;
    __syncthreads();
    int v = blockIdx.x * blockDim.x + threadIdx.x;
    if (v < N) atomicAdd(&hist[batch[v]], 1);
    __syncthreads();
    if (threadIdx.x < NUM_GRAPHS && hist[threadIdx.x] > 0)
        atomicAdd(&pcnt[threadIdx.x], (float)hist[threadIdx.x]);
}

// ---- pooling: 64 nodes/block, register accumulator, flush on graph change --
#define POOL_CHUNK 64
__global__ __launch_bounds__(256) void k_pool(
        const float* __restrict__ h, const int* __restrict__ batch,
        float* __restrict__ psum, int N) {
    int tid = threadIdx.x;  // feature
    int n0 = blockIdx.x * POOL_CHUNK;
    int n1 = n0 + POOL_CHUNK;
    if (n1 > N) n1 = N;
    int gcur = batch[n0];  // sorted -> uniform scalar
    float racc = 0.0f;
    for (int n = n0; n < n1; ++n) {
        int g = batch[n];
        if (g != gcur) {
            atomicAdd(&psum[gcur * 256 + tid], racc);
            racc = 0.0f;
            gcur = g;
        }
        racc += h[(long)n * 256 + tid];
    }
    atomicAdd(&psum[gcur * 256 + tid], racc);
}

// ---- final FC --------------------------------------------------------------
__global__ void k_fc(const float* __restrict__ psum, const float* __restrict__ pcnt,
                     const float* __restrict__ Wfc, const float* __restrict__ bfc,
                     float* __restrict__ out) {
    int tid = blockIdx.x * blockDim.x + threadIdx.x;
    if (tid >= NUM_GRAPHS * NUM_CLASSES) return;
    int g = tid / NUM_CLASSES;
    int c = tid % NUM_CLASSES;
    float s = 0.0f;
#pragma unroll 8
    for (int k = 0; k < 256; ++k) s = fmaf(psum[g * 256 + k], Wfc[k * NUM_CLASSES + c], s);
    float cnt = pcnt[g];
    cnt = cnt > 1.0f ? cnt : 1.0f;
    out[tid] = s / cnt + bfc[c];
}

extern "C" void kernel_launch(void* const* d_in, const int* in_sizes, int n_in,
                              void* d_out, int out_size, void* d_ws, size_t ws_size,
                              hipStream_t stream) {
    const float* x     = (const float*)d_in[0];
    const int*   ei    = (const int*)d_in[1];
    const int*   batch = (const int*)d_in[2];
    const float* W1    = (const float*)d_in[3];
    const float* b1    = (const float*)d_in[4];
    const float* W2    = (const float*)d_in[5];
    const float* b2    = (const float*)d_in[6];
    const float* W3    = (const float*)d_in[7];
    const float* b3    = (const float*)d_in[8];
    const float* Wfc   = (const float*)d_in[9];
    const float* bfc   = (const float*)d_in[10];
    float* out = (float*)d_out;

    const int* row = ei;            // src
    const int* col = ei + N_EDGES;  // dst

    // workspace layout (~81 MB)
    float* bufA   = (float*)d_ws;                        // N*256
    float* bufB   = bufA + (size_t)N_NODES * 256;        // N*128
    float* dinv   = bufB + (size_t)N_NODES * 128;        // N
    float* psum   = dinv + N_NODES;                      // 16*256
    float* pcnt   = psum + NUM_GRAPHS * 256;             // 16
    int*   degi   = (int*)(pcnt + NUM_GRAPHS);           // N
    int*   rowptr = degi + N_NODES;                      // N+1
    int*   cursor = rowptr + N_NODES + 1;                // N
    int*   csrsrc = cursor + N_NODES;                    // E
    int*   bsum   = csrsrc + N_EDGES;                    // SCAN_BLOCKS

    hipMemsetAsync(degi, 0, N_NODES * sizeof(int), stream);
    hipMemsetAsync(cursor, 0, N_NODES * sizeof(int), stream);
    hipMemsetAsync(psum, 0, (NUM_GRAPHS * 256 + NUM_GRAPHS) * sizeof(float), stream);

    // ---- CSR build + norms ----
    k_deg<<<nblk(N_EDGES), 256, 0, stream>>>(col, degi, N_EDGES);
    k_dinv<<<nblk(N_NODES), 256, 0, stream>>>(degi, dinv, N_NODES);
    k_scan1<<<SCAN_BLOCKS, 256, 0, stream>>>(degi, rowptr, bsum, N_NODES);
    k_scan2<<<1, 256, 0, stream>>>(bsum, SCAN_BLOCKS);
    k_scan3<<<SCAN_BLOCKS, 256, 0, stream>>>(rowptr, bsum, N_NODES);
    k_fill<<<nblk(N_EDGES), 256, 0, stream>>>(row, col, rowptr, cursor, csrsrc, N_EDGES);

    int prop_blocks = (N_NODES + 3) / 4;   // 4 nodes (waves) per block
    int gemm_blocks = (N_NODES + 31) / 32; // 32-node tiles

    // ---- layer 1: p1 = A~ x [N,3]; h1 = relu(p1 W1 + b1) [N,64] ----
    k_prop3<<<nblk(N_NODES), 256, 0, stream>>>(x, dinv, rowptr, csrsrc, bufB, N_NODES);
    k_lin3<<<nblk((long)N_NODES * 64), 256, 0, stream>>>(bufB, W1, b1, bufA, N_NODES);

    // ---- layer 2: p2 = A~ h1 [N,64]; h2 = relu(p2 W2 + b2) [N,128] ----
    k_prop<64><<<prop_blocks, 256, 0, stream>>>(bufA, dinv, rowptr, csrsrc, bufB, N_NODES);
    k_gemm<64, 128, true><<<gemm_blocks, 256, 0, stream>>>(bufB, W2, b2, bufA, N_NODES);

    // ---- layer 3: p3 = A~ h2 [N,128]; h3 = relu(p3 W3 + b3) [N,256] ----
    k_prop<128><<<prop_blocks, 256, 0, stream>>>(bufA, dinv, rowptr, csrsrc, bufB, N_NODES);
    k_gemm<128, 256, true><<<gemm_blocks, 256, 0, stream>>>(bufB, W3, b3, bufA, N_NODES);

    // ---- global mean pool + FC ----
    k_cnt<<<nblk(N_NODES), 256, 0, stream>>>(batch, pcnt, N_NODES);
    int pool_blocks = (N_NODES + POOL_CHUNK - 1) / POOL_CHUNK;
    k_pool<<<pool_blocks, 256, 0, stream>>>(bufA, batch, psum, N_NODES);
    k_fc<<<nblk(NUM_GRAPHS * NUM_CLASSES), 256, 0, stream>>>(psum, pcnt, Wfc, bfc, out);
}

// Round 5
// 387.351 us; speedup vs baseline: 14.2354x; 1.0041x over previous
//
#include <hip/hip_runtime.h>

#define N_NODES 50000
#define N_EDGES 800000
#define NUM_GRAPHS 16
#define NUM_CLASSES 247
#define SCAN_BLOCKS ((N_NODES + 255) / 256)  // 196

static inline int nblk(long n) { return (int)((n + 255) / 256); }

// ---- degree histogram (int) ------------------------------------------------
__global__ void k_deg(const int* __restrict__ col, int* __restrict__ degi, int E) {
    int e = blockIdx.x * blockDim.x + threadIdx.x;
    if (e < E) atomicAdd(&degi[col[e]], 1);
}

// ---- hierarchical exclusive scan: degi -> rowptr[N+1] ----------------------
__global__ __launch_bounds__(256) void k_scan1(const int* __restrict__ degi,
                                               int* __restrict__ rowptr,
                                               int* __restrict__ bsum, int N) {
    __shared__ int buf[256];
    int t = threadIdx.x;
    int i = blockIdx.x * 256 + t;
    int v = (i < N) ? degi[i] : 0;
    buf[t] = v;
    __syncthreads();
#pragma unroll
    for (int off = 1; off < 256; off <<= 1) {
        int tmp = (t >= off) ? buf[t - off] : 0;
        __syncthreads();
        if (t >= off) buf[t] += tmp;
        __syncthreads();
    }
    if (i < N) rowptr[i] = buf[t] - v;  // exclusive within block
    if (t == 255) bsum[blockIdx.x] = buf[255];
}

__global__ __launch_bounds__(256) void k_scan2(int* __restrict__ bsum, int nb) {
    __shared__ int buf[256];
    int t = threadIdx.x;
    int v = (t < nb) ? bsum[t] : 0;
    buf[t] = v;
    __syncthreads();
#pragma unroll
    for (int off = 1; off < 256; off <<= 1) {
        int tmp = (t >= off) ? buf[t - off] : 0;
        __syncthreads();
        if (t >= off) buf[t] += tmp;
        __syncthreads();
    }
    if (t < nb) bsum[t] = buf[t] - v;  // exclusive
}

// phase 3: add block offsets; also compute dinv (folded k_dinv)
__global__ __launch_bounds__(256) void k_scan3(int* __restrict__ rowptr,
                                               const int* __restrict__ bsum,
                                               const int* __restrict__ degi,
                                               float* __restrict__ dinv, int N) {
    int i = blockIdx.x * 256 + (int)threadIdx.x;
    if (i < N) {
        rowptr[i] += bsum[blockIdx.x];
        dinv[i] = rsqrtf((float)degi[i] + 1.0f);  // +1 = self loop
    }
    if (i == 0) rowptr[N] = N_EDGES;
}

// ---- CSR fill: csr_src[rowptr[c] + pos] = r --------------------------------
__global__ void k_fill(const int* __restrict__ row, const int* __restrict__ col,
                       const int* __restrict__ rowptr, int* __restrict__ cursor,
                       int* __restrict__ csr_src, int E) {
    int e = blockIdx.x * blockDim.x + threadIdx.x;
    if (e >= E) return;
    int c = col[e];
    int pos = atomicAdd(&cursor[c], 1);
    csr_src[rowptr[c] + pos] = row[e];
}

// ---- propagation, F=3 (raw x), thread per node -----------------------------
__global__ void k_prop3(const float* __restrict__ x, const float* __restrict__ dinv,
                        const int* __restrict__ rowptr, const int* __restrict__ csr_src,
                        float* __restrict__ out, int N) {
    int v = blockIdx.x * blockDim.x + threadIdx.x;
    if (v >= N) return;
    float dv = dinv[v];
    float a0 = dv * x[v * 3 + 0];
    float a1 = dv * x[v * 3 + 1];
    float a2 = dv * x[v * 3 + 2];
    int j1 = rowptr[v + 1];
    for (int j = rowptr[v]; j < j1; ++j) {
        int r = csr_src[j];
        float dr = dinv[r];
        a0 += dr * x[r * 3 + 0];
        a1 += dr * x[r * 3 + 1];
        a2 += dr * x[r * 3 + 2];
    }
    out[v * 3 + 0] = dv * a0;
    out[v * 3 + 1] = dv * a1;
    out[v * 3 + 2] = dv * a2;
}

// ---- propagation, F in {64,128}: wave per node, 8-edge unroll --------------
// Same fma order per acc[k] as the scalar loop -> bit-identical results.
template <int F>
__global__ __launch_bounds__(256) void k_prop(
        const float* __restrict__ h, const float* __restrict__ dinv,
        const int* __restrict__ rowptr, const int* __restrict__ csr_src,
        float* __restrict__ out, int N) {
    constexpr int K = F / 64;  // contiguous floats per lane (1 or 2)
    int wave = threadIdx.x >> 6;
    int lane = threadIdx.x & 63;
    int v = blockIdx.x * 4 + wave;
    if (v >= N) return;
    float dv = dinv[v];
    float acc[K];
    const float* hv = h + (long)v * F + lane * K;
#pragma unroll
    for (int k = 0; k < K; ++k) acc[k] = dv * hv[k];
    int j0 = __builtin_amdgcn_readfirstlane(rowptr[v]);
    int j1 = __builtin_amdgcn_readfirstlane(rowptr[v + 1]);
    int j = j0;
    for (; j + 8 <= j1; j += 8) {
        int r[8];
        float d[8];
        const float* hp[8];
#pragma unroll
        for (int u = 0; u < 8; ++u) r[u] = csr_src[j + u];
#pragma unroll
        for (int u = 0; u < 8; ++u) d[u] = dinv[r[u]];
#pragma unroll
        for (int u = 0; u < 8; ++u) hp[u] = h + (long)r[u] * F + lane * K;
        float t[8][K];
#pragma unroll
        for (int u = 0; u < 8; ++u)
#pragma unroll
            for (int k = 0; k < K; ++k) t[u][k] = hp[u][k];
#pragma unroll
        for (int u = 0; u < 8; ++u)
#pragma unroll
            for (int k = 0; k < K; ++k) acc[k] = fmaf(d[u], t[u][k], acc[k]);
    }
    for (; j + 4 <= j1; j += 4) {
        int r0 = csr_src[j + 0], r1 = csr_src[j + 1];
        int r2 = csr_src[j + 2], r3 = csr_src[j + 3];
        float d0 = dinv[r0], d1 = dinv[r1], d2 = dinv[r2], d3 = dinv[r3];
        const float* h0 = h + (long)r0 * F + lane * K;
        const float* h1 = h + (long)r1 * F + lane * K;
        const float* h2 = h + (long)r2 * F + lane * K;
        const float* h3 = h + (long)r3 * F + lane * K;
#pragma unroll
        for (int k = 0; k < K; ++k) {
            float t0 = h0[k], t1 = h1[k], t2 = h2[k], t3 = h3[k];
            acc[k] = fmaf(d0, t0, acc[k]);
            acc[k] = fmaf(d1, t1, acc[k]);
            acc[k] = fmaf(d2, t2, acc[k]);
            acc[k] = fmaf(d3, t3, acc[k]);
        }
    }
    for (; j < j1; ++j) {
        int r = csr_src[j];
        float dr = dinv[r];
        const float* hr = h + (long)r * F + lane * K;
#pragma unroll
        for (int k = 0; k < K; ++k) acc[k] = fmaf(dr, hr[k], acc[k]);
    }
    float* ov = out + (long)v * F + lane * K;
#pragma unroll
    for (int k = 0; k < K; ++k) ov[k] = dv * acc[k];
}

// ---- naive linear for tiny FIN=3 layer -------------------------------------
__global__ void k_lin3(const float* __restrict__ h, const float* __restrict__ W,
                       const float* __restrict__ b, float* __restrict__ out, int N) {
    long tid = (long)blockIdx.x * blockDim.x + threadIdx.x;
    if (tid >= (long)N * 64) return;
    int v = (int)(tid / 64);
    int f = (int)(tid % 64);
    const float* hr = h + (long)v * 3;
    float s = b[f];
    s = fmaf(hr[0], W[0 * 64 + f], s);
    s = fmaf(hr[1], W[1 * 64 + f], s);
    s = fmaf(hr[2], W[2 * 64 + f], s);
    out[tid] = s > 0.0f ? s : 0.0f;
}

// ---- register-tiled GEMM: 64-node tile, VPT nodes/thread -------------------
// All lanes of a wave share vg -> hs reads are wave-broadcast (conflict-free).
template <int FIN, int FOUT, bool RELU>
__global__ __launch_bounds__(256) void k_gemm(
        const float* __restrict__ h, const float* __restrict__ W,
        const float* __restrict__ b, float* __restrict__ out, int N) {
    constexpr int TILE = 64;        // nodes per block
    constexpr int FG = FOUT / 4;    // f-groups (float4)
    constexpr int VG = 256 / FG;    // v-groups
    constexpr int VPT = TILE / VG;  // nodes per thread (16 for FOUT=256, 8 for 128)
    constexpr int ROWF4 = FIN / 4;  // float4s per h row
    __shared__ float hs[TILE][FIN]; // FIN=128 -> 32 KB
    int t = threadIdx.x;
    int fg = t % FG;
    int vg = t / FG;
    int v0 = blockIdx.x * TILE;
    for (int i = t; i < TILE * ROWF4; i += 256) {
        int vv = i / ROWF4, kk = i % ROWF4;
        int vsrc = v0 + vv;
        if (vsrc >= N) vsrc = N - 1;  // tail: clamp, stores are guarded
        float4 val = ((const float4*)(h + (long)vsrc * FIN))[kk];
        *(float4*)&hs[vv][kk * 4] = val;
    }
    __syncthreads();
    float4 bias = ((const float4*)b)[fg];
    float acc[VPT][4];
#pragma unroll
    for (int i = 0; i < VPT; ++i) {
        acc[i][0] = bias.x; acc[i][1] = bias.y;
        acc[i][2] = bias.z; acc[i][3] = bias.w;
    }
    const float4* Wf4 = (const float4*)W;
#pragma unroll 4
    for (int k = 0; k < FIN; ++k) {
        float4 w = Wf4[k * FG + fg];
#pragma unroll
        for (int i = 0; i < VPT; ++i) {
            float hvv = hs[vg * VPT + i][k];
            acc[i][0] = fmaf(hvv, w.x, acc[i][0]);
            acc[i][1] = fmaf(hvv, w.y, acc[i][1]);
            acc[i][2] = fmaf(hvv, w.z, acc[i][2]);
            acc[i][3] = fmaf(hvv, w.w, acc[i][3]);
        }
    }
#pragma unroll
    for (int i = 0; i < VPT; ++i) {
        int v = v0 + vg * VPT + i;
        if (v < N) {
            float4 r;
            r.x = RELU ? fmaxf(acc[i][0], 0.0f) : acc[i][0];
            r.y = RELU ? fmaxf(acc[i][1], 0.0f) : acc[i][1];
            r.z = RELU ? fmaxf(acc[i][2], 0.0f) : acc[i][2];
            r.w = RELU ? fmaxf(acc[i][3], 0.0f) : acc[i][3];
            ((float4*)(out + (long)v * FOUT))[fg] = r;
        }
    }
}

// ---- graph-size histogram (counts), LDS-staged -----------------------------
__global__ void k_cnt(const int* __restrict__ batch, float* __restrict__ pcnt, int N) {
    __shared__ int hist[NUM_GRAPHS];
    if (threadIdx.x < NUM_GRAPHS) hist[threadIdx.x] = 0;
    __syncthreads();
    int v = blockIdx.x * blockDim.x + threadIdx.x;
    if (v < N) atomicAdd(&hist[batch[v]], 1);
    __syncthreads();
    if (threadIdx.x < NUM_GRAPHS && hist[threadIdx.x] > 0)
        atomicAdd(&pcnt[threadIdx.x], (float)hist[threadIdx.x]);
}

// ---- pooling: 64 nodes/block, register accumulator, flush on graph change --
#define POOL_CHUNK 64
__global__ __launch_bounds__(256) void k_pool(
        const float* __restrict__ h, const int* __restrict__ batch,
        float* __restrict__ psum, int N) {
    int tid = threadIdx.x;  // feature
    int n0 = blockIdx.x * POOL_CHUNK;
    int n1 = n0 + POOL_CHUNK;
    if (n1 > N) n1 = N;
    int gcur = batch[n0];  // sorted -> uniform scalar
    float racc = 0.0f;
    for (int n = n0; n < n1; ++n) {
        int g = batch[n];
        if (g != gcur) {
            atomicAdd(&psum[gcur * 256 + tid], racc);
            racc = 0.0f;
            gcur = g;
        }
        racc += h[(long)n * 256 + tid];
    }
    atomicAdd(&psum[gcur * 256 + tid], racc);
}

// ---- final FC --------------------------------------------------------------
__global__ void k_fc(const float* __restrict__ psum, const float* __restrict__ pcnt,
                     const float* __restrict__ Wfc, const float* __restrict__ bfc,
                     float* __restrict__ out) {
    int tid = blockIdx.x * blockDim.x + threadIdx.x;
    if (tid >= NUM_GRAPHS * NUM_CLASSES) return;
    int g = tid / NUM_CLASSES;
    int c = tid % NUM_CLASSES;
    float s = 0.0f;
#pragma unroll 8
    for (int k = 0; k < 256; ++k) s = fmaf(psum[g * 256 + k], Wfc[k * NUM_CLASSES + c], s);
    float cnt = pcnt[g];
    cnt = cnt > 1.0f ? cnt : 1.0f;
    out[tid] = s / cnt + bfc[c];
}

extern "C" void kernel_launch(void* const* d_in, const int* in_sizes, int n_in,
                              void* d_out, int out_size, void* d_ws, size_t ws_size,
                              hipStream_t stream) {
    const float* x     = (const float*)d_in[0];
    const int*   ei    = (const int*)d_in[1];
    const int*   batch = (const int*)d_in[2];
    const float* W1    = (const float*)d_in[3];
    const float* b1    = (const float*)d_in[4];
    const float* W2    = (const float*)d_in[5];
    const float* b2    = (const float*)d_in[6];
    const float* W3    = (const float*)d_in[7];
    const float* b3    = (const float*)d_in[8];
    const float* Wfc   = (const float*)d_in[9];
    const float* bfc   = (const float*)d_in[10];
    float* out = (float*)d_out;

    const int* row = ei;            // src
    const int* col = ei + N_EDGES;  // dst

    // workspace layout (~81 MB)
    float* bufA   = (float*)d_ws;                        // N*256
    float* bufB   = bufA + (size_t)N_NODES * 256;        // N*128
    float* dinv   = bufB + (size_t)N_NODES * 128;        // N
    float* psum   = dinv + N_NODES;                      // 16*256
    float* pcnt   = psum + NUM_GRAPHS * 256;             // 16
    int*   degi   = (int*)(pcnt + NUM_GRAPHS);           // N
    int*   rowptr = degi + N_NODES;                      // N+1
    int*   cursor = rowptr + N_NODES + 1;                // N
    int*   csrsrc = cursor + N_NODES;                    // E
    int*   bsum   = csrsrc + N_EDGES;                    // SCAN_BLOCKS

    hipMemsetAsync(degi, 0, N_NODES * sizeof(int), stream);
    hipMemsetAsync(cursor, 0, N_NODES * sizeof(int), stream);
    hipMemsetAsync(psum, 0, (NUM_GRAPHS * 256 + NUM_GRAPHS) * sizeof(float), stream);

    // ---- CSR build + norms ----
    k_deg<<<nblk(N_EDGES), 256, 0, stream>>>(col, degi, N_EDGES);
    k_scan1<<<SCAN_BLOCKS, 256, 0, stream>>>(degi, rowptr, bsum, N_NODES);
    k_scan2<<<1, 256, 0, stream>>>(bsum, SCAN_BLOCKS);
    k_scan3<<<SCAN_BLOCKS, 256, 0, stream>>>(rowptr, bsum, degi, dinv, N_NODES);
    k_fill<<<nblk(N_EDGES), 256, 0, stream>>>(row, col, rowptr, cursor, csrsrc, N_EDGES);

    int prop_blocks = (N_NODES + 3) / 4;   // 4 nodes (waves) per block
    int gemm_blocks = (N_NODES + 63) / 64; // 64-node tiles

    // ---- layer 1: p1 = A~ x [N,3]; h1 = relu(p1 W1 + b1) [N,64] ----
    k_prop3<<<nblk(N_NODES), 256, 0, stream>>>(x, dinv, rowptr, csrsrc, bufB, N_NODES);
    k_lin3<<<nblk((long)N_NODES * 64), 256, 0, stream>>>(bufB, W1, b1, bufA, N_NODES);

    // ---- layer 2: p2 = A~ h1 [N,64]; h2 = relu(p2 W2 + b2) [N,128] ----
    k_prop<64><<<prop_blocks, 256, 0, stream>>>(bufA, dinv, rowptr, csrsrc, bufB, N_NODES);
    k_gemm<64, 128, true><<<gemm_blocks, 256, 0, stream>>>(bufB, W2, b2, bufA, N_NODES);

    // ---- layer 3: p3 = A~ h2 [N,128]; h3 = relu(p3 W3 + b3) [N,256] ----
    k_prop<128><<<prop_blocks, 256, 0, stream>>>(bufA, dinv, rowptr, csrsrc, bufB, N_NODES);
    k_gemm<128, 256, true><<<gemm_blocks, 256, 0, stream>>>(bufB, W3, b3, bufA, N_NODES);

    // ---- global mean pool + FC ----
    k_cnt<<<nblk(N_NODES), 256, 0, stream>>>(batch, pcnt, N_NODES);
    int pool_blocks = (N_NODES + POOL_CHUNK - 1) / POOL_CHUNK;
    k_pool<<<pool_blocks, 256, 0, stream>>>(bufA, batch, psum, N_NODES);
    k_fc<<<nblk(NUM_GRAPHS * NUM_CLASSES), 256, 0, stream>>>(psum, pcnt, Wfc, bfc, out);
}